// Round 12
// baseline (402.198 us; speedup 1.0000x reference)
//
#include <hip/hip_runtime.h>

#define D_MODEL 1024
#define NUM_HEADS 16
#define SEQ 2048
#define BATCH 2

typedef __attribute__((ext_vector_type(8))) short bf16x8;
typedef __attribute__((ext_vector_type(4))) float f32x4;

__device__ __forceinline__ float bf2f(unsigned short u) {
    return __uint_as_float(((unsigned int)u) << 16);
}
__device__ __forceinline__ unsigned short f2bf(float f) {
    unsigned int u = __float_as_uint(f);
    return (unsigned short)((u + 0x7FFFu + ((u >> 16) & 1u)) >> 16);   // RTNE
}
__device__ __forceinline__ ushort4 pack4(float4 v) {
    return make_ushort4(f2bf(v.x), f2bf(v.y), f2bf(v.z), f2bf(v.w));
}

// fp32 -> bf16 bulk convert (one float4 -> ushort4 per thread).
__global__ __launch_bounds__(256) void conv_kernel(
    const float* __restrict__ src, unsigned short* __restrict__ dst, int n4)
{
    int i = blockIdx.x * 256 + threadIdx.x;
    if (i < n4) {
        float4 v = reinterpret_cast<const float4*>(src)[i];
        reinterpret_cast<ushort4*>(dst)[i] = pack4(v);
    }
}

// MFMA NT-GEMM: C[m,n] = sum_i x[m,i] * W[n,i]. x fp32, W bf16 (pre-converted).
// 128x128 tile, BK=32. 1D grid, XCD-swizzled: lin = b + 8*(which + 3*y).
// Q,K: RoPE fused, [b][h][s][d]. V: TRANSPOSED write [b][h][d][s].
__global__ __launch_bounds__(256) void qkv_mfma_kernel(
    const float* __restrict__ x,
    const unsigned short* __restrict__ w3,   // [3][1024][1024] bf16
    unsigned short* __restrict__ qb, unsigned short* __restrict__ kb,
    unsigned short* __restrict__ vt)
{
    const int lin = blockIdx.x;
    const int b = lin & 7;
    const int t = lin >> 3;
    const int which = t % 3;
    const int y = t / 3;
    const unsigned short* __restrict__ W = w3 + (size_t)which * 1048576;
    const int m0 = y * 128;
    const int n0g = b * 128;

    __shared__ __align__(16) unsigned short As[128][40];  // 80 B stride
    __shared__ __align__(16) unsigned short Bs[128][40];

    const int tid = threadIdx.x;
    const int w = tid >> 6;
    const int lane = tid & 63;
    const int quad = lane >> 4;
    const int c15 = lane & 15;
    const int qm = w >> 1, qn = w & 1;

    const int srow = tid >> 1;
    const int scol = (tid & 1) * 16;

    f32x4 acc[4][4];
#pragma unroll
    for (int mi = 0; mi < 4; mi++)
#pragma unroll
        for (int ni = 0; ni < 4; ni++) acc[mi][ni] = (f32x4){0.f, 0.f, 0.f, 0.f};

    for (int kb0 = 0; kb0 < 1024; kb0 += 32) {
        const float* ap = x + (size_t)(m0 + srow) * 1024 + kb0 + scol;
        float4 a0 = *reinterpret_cast<const float4*>(ap + 0);
        float4 a1 = *reinterpret_cast<const float4*>(ap + 4);
        float4 a2 = *reinterpret_cast<const float4*>(ap + 8);
        float4 a3 = *reinterpret_cast<const float4*>(ap + 12);
        const unsigned short* wp = W + (size_t)(n0g + srow) * 1024 + kb0 + scol;
        uint4 b0 = *reinterpret_cast<const uint4*>(wp);
        uint4 b1 = *reinterpret_cast<const uint4*>(wp + 8);

        __syncthreads();
        {
            ushort4* ad = reinterpret_cast<ushort4*>(&As[srow][scol]);
            ad[0] = pack4(a0); ad[1] = pack4(a1); ad[2] = pack4(a2); ad[3] = pack4(a3);
            uint4* bd = reinterpret_cast<uint4*>(&Bs[srow][scol]);
            bd[0] = b0; bd[1] = b1;
        }
        __syncthreads();

        bf16x8 af[4], bfr[4];
#pragma unroll
        for (int mi = 0; mi < 4; mi++)
            af[mi] = *reinterpret_cast<const bf16x8*>(&As[qm * 64 + mi * 16 + c15][quad * 8]);
#pragma unroll
        for (int ni = 0; ni < 4; ni++)
            bfr[ni] = *reinterpret_cast<const bf16x8*>(&Bs[qn * 64 + ni * 16 + c15][quad * 8]);
#pragma unroll
        for (int mi = 0; mi < 4; mi++)
#pragma unroll
            for (int ni = 0; ni < 4; ni++)
                acc[mi][ni] = __builtin_amdgcn_mfma_f32_16x16x32_bf16(af[mi], bfr[ni], acc[mi][ni], 0, 0, 0);
    }

    // Epilogue: RoPE (Q,K) in registers -> wave-private LDS stage -> coalesced
    // stores. Wave's n-range = one head: h = b*2 + qn.
    __syncthreads();
    unsigned short* stg = &As[0][0] + w * (16 * 72);   // 16 rows x 72 stride, per wave
    const int hq = b * 2 + qn;
    unsigned short* outp = (which == 0) ? qb : kb;

    float invf[4];
#pragma unroll
    for (int ni = 0; ni < 4; ni++)
        invf[ni] = powf(10000.0f, -((float)(((ni * 16 + c15) & 63) >> 1)) / 32.0f);
    const int odd = c15 & 1;

#pragma unroll
    for (int mi = 0; mi < 4; mi++) {
#pragma unroll
        for (int r = 0; r < 4; r++) {
            int m = m0 + qm * 64 + mi * 16 + quad * 4 + r;
            int s = m & (SEQ - 1);
#pragma unroll
            for (int ni = 0; ni < 4; ni++) {
                float val = acc[mi][ni][r];
                float res;
                if (which < 2) {
                    float part = __shfl_xor(val, 1);
                    float sn, cs;
                    sincosf((float)s * invf[ni], &sn, &cs);
                    res = odd ? (part * sn + val * cs) : (val * cs - part * sn);
                } else {
                    res = val;
                }
                stg[(quad * 4 + r) * 72 + ni * 16 + c15] = f2bf(res);
            }
        }
        if (which < 2) {
            // rows of [s][d]: 4 lanes per row, 32 B each -> 128 B contiguous
            int row = lane >> 2;
            int ch = lane & 3;
            int m = m0 + qm * 64 + mi * 16 + row;
            int s = m & (SEQ - 1);
            int bb = m >> 11;
            size_t ob = (((size_t)bb * NUM_HEADS + hq) * SEQ + s) * 64 + ch * 16;
            uint4 v0 = *reinterpret_cast<const uint4*>(&stg[row * 72 + ch * 16]);
            uint4 v1 = *reinterpret_cast<const uint4*>(&stg[row * 72 + ch * 16 + 8]);
            *reinterpret_cast<uint4*>(&outp[ob]) = v0;
            *reinterpret_cast<uint4*>(&outp[ob + 8]) = v1;
        } else {
            // transposed write to vt[b][h][d][s]: lane = d, 16 s values = 32 B
            int mbase = m0 + qm * 64 + mi * 16;
            int bb = mbase >> 11;
            int s_base = mbase & (SEQ - 1);
            unsigned short tmp[16];
#pragma unroll
            for (int sl = 0; sl < 16; sl++) tmp[sl] = stg[sl * 72 + lane];
            size_t ob = (((size_t)bb * NUM_HEADS + hq) * 64 + lane) * SEQ + s_base;
            *reinterpret_cast<uint4*>(&vt[ob])     = *reinterpret_cast<uint4*>(&tmp[0]);
            *reinterpret_cast<uint4*>(&vt[ob + 8]) = *reinterpret_cast<uint4*>(&tmp[8]);
        }
    }
}

// MFMA flash attention, barrier-free K-loop. Block = 64-row Q-tile x (b,h);
// K and V^T fragments straight from global; only wave-private Pl LDS.
__global__ __launch_bounds__(256) void attn_kernel(
    const unsigned short* __restrict__ qb, const unsigned short* __restrict__ kb,
    const unsigned short* __restrict__ vt, unsigned short* __restrict__ ab)
{
    const int it = (gridDim.x - 1) - blockIdx.x;   // heavy tiles dispatch first
    const int bh = blockIdx.y;
    const int b = bh >> 4, h = bh & 15;
    const size_t base = (size_t)bh * SEQ * 64;     // qb/kb [b][h][s][d]
    const size_t vbase = (size_t)bh * 64 * SEQ;    // vt [b][h][d][s]
    const int tid = threadIdx.x;
    const int w = tid >> 6;
    const int lane = tid & 63;
    const int quad = lane >> 4;
    const int c15 = lane & 15;
    const int i0 = it * 64;

    __shared__ __align__(16) unsigned short Pl[64][72];   // wave-private rows

    const int qrow = i0 + w * 16 + c15;
    bf16x8 qf0 = *reinterpret_cast<const bf16x8*>(&qb[base + (size_t)qrow * 64 + quad * 8]);
    bf16x8 qf1 = *reinterpret_cast<const bf16x8*>(&qb[base + (size_t)qrow * 64 + 32 + quad * 8]);

    float m_st[4], l_st[4];
    f32x4 Oc[4];
#pragma unroll
    for (int r = 0; r < 4; r++) { m_st[r] = -1e30f; l_st[r] = 0.f; }
#pragma unroll
    for (int t = 0; t < 4; t++) Oc[t] = (f32x4){0.f, 0.f, 0.f, 0.f};

    for (int jt = 0; jt <= it; jt++) {
        const int j0 = jt * 64;

        f32x4 sc[4];
#pragma unroll
        for (int t = 0; t < 4; t++) sc[t] = (f32x4){0.f, 0.f, 0.f, 0.f};
#pragma unroll
        for (int t = 0; t < 4; t++) {
            const unsigned short* kr = &kb[base + (size_t)(j0 + t * 16 + c15) * 64];
            bf16x8 k0 = *reinterpret_cast<const bf16x8*>(kr + quad * 8);
            bf16x8 k1 = *reinterpret_cast<const bf16x8*>(kr + 32 + quad * 8);
            sc[t] = __builtin_amdgcn_mfma_f32_16x16x32_bf16(qf0, k0, sc[t], 0, 0, 0);
            sc[t] = __builtin_amdgcn_mfma_f32_16x16x32_bf16(qf1, k1, sc[t], 0, 0, 0);
        }

#pragma unroll
        for (int t = 0; t < 4; t++)
#pragma unroll
            for (int r = 0; r < 4; r++) sc[t][r] *= 0.125f;
        if (jt == it) {
#pragma unroll
            for (int t = 0; t < 4; t++) {
                int gj = j0 + t * 16 + c15;
#pragma unroll
                for (int r = 0; r < 4; r++) {
                    int gi = i0 + w * 16 + quad * 4 + r;
                    if (gj > gi) sc[t][r] = -1e30f;
                }
            }
        }

        float mnew[4], alpha[4], rsum[4];
#pragma unroll
        for (int r = 0; r < 4; r++) {
            float tm = fmaxf(fmaxf(sc[0][r], sc[1][r]), fmaxf(sc[2][r], sc[3][r]));
            tm = fmaxf(tm, __shfl_xor(tm, 1));
            tm = fmaxf(tm, __shfl_xor(tm, 2));
            tm = fmaxf(tm, __shfl_xor(tm, 4));
            tm = fmaxf(tm, __shfl_xor(tm, 8));
            mnew[r] = fmaxf(m_st[r], tm);
            alpha[r] = __expf(m_st[r] - mnew[r]);
            rsum[r] = 0.f;
        }
#pragma unroll
        for (int t = 0; t < 4; t++) {
#pragma unroll
            for (int r = 0; r < 4; r++) {
                float p = __expf(sc[t][r] - mnew[r]);
                rsum[r] += p;
                Pl[w * 16 + quad * 4 + r][t * 16 + c15] = f2bf(p);
            }
        }
#pragma unroll
        for (int r = 0; r < 4; r++) {
            float s = rsum[r];
            s += __shfl_xor(s, 1);
            s += __shfl_xor(s, 2);
            s += __shfl_xor(s, 4);
            s += __shfl_xor(s, 8);
            l_st[r] = l_st[r] * alpha[r] + s;
            m_st[r] = mnew[r];
#pragma unroll
            for (int t = 0; t < 4; t++) Oc[t][r] *= alpha[r];
        }

        bf16x8 ap0 = *reinterpret_cast<const bf16x8*>(&Pl[w * 16 + c15][quad * 8]);
        bf16x8 ap1 = *reinterpret_cast<const bf16x8*>(&Pl[w * 16 + c15][32 + quad * 8]);
#pragma unroll
        for (int t = 0; t < 4; t++) {
            const unsigned short* vr = &vt[vbase + (size_t)(t * 16 + c15) * SEQ + j0];
            bf16x8 bv0 = *reinterpret_cast<const bf16x8*>(vr + quad * 8);
            bf16x8 bv1 = *reinterpret_cast<const bf16x8*>(vr + 32 + quad * 8);
            Oc[t] = __builtin_amdgcn_mfma_f32_16x16x32_bf16(ap0, bv0, Oc[t], 0, 0, 0);
            Oc[t] = __builtin_amdgcn_mfma_f32_16x16x32_bf16(ap1, bv1, Oc[t], 0, 0, 0);
        }
    }

    // Epilogue: stage O into Pl, coalesced uint4 stores.
#pragma unroll
    for (int r = 0; r < 4; r++) {
        float inv = 1.0f / l_st[r];
#pragma unroll
        for (int t = 0; t < 4; t++)
            Pl[w * 16 + quad * 4 + r][t * 16 + c15] = f2bf(Oc[t][r] * inv);
    }
    {
        int row = lane >> 2;
        int ch = lane & 3;
        int gi = i0 + w * 16 + row;
        size_t ob = ((size_t)b * SEQ + gi) * 1024 + h * 64 + ch * 16;
        uint4 v0 = *reinterpret_cast<const uint4*>(&Pl[w * 16 + row][ch * 16]);
        uint4 v1 = *reinterpret_cast<const uint4*>(&Pl[w * 16 + row][ch * 16 + 8]);
        *reinterpret_cast<uint4*>(&ab[ob]) = v0;
        *reinterpret_cast<uint4*>(&ab[ob + 8]) = v1;
    }
}

// MFMA NT-GEMM: out[m,n] = sum_i ab[m,i] * Wo[n,i]; both bf16, out fp32.
__global__ __launch_bounds__(256) void out_mfma_kernel(
    const unsigned short* __restrict__ A, const unsigned short* __restrict__ Wob,
    float* __restrict__ out)
{
    const int lin = blockIdx.x;
    const int b = lin & 7;
    const int y = lin >> 3;
    const int m0 = y * 128;
    const int n0g = b * 128;

    __shared__ __align__(16) unsigned short As[128][40];
    __shared__ __align__(16) unsigned short Bs[128][40];

    const int tid = threadIdx.x;
    const int w = tid >> 6;
    const int lane = tid & 63;
    const int quad = lane >> 4;
    const int c15 = lane & 15;
    const int qm = w >> 1, qn = w & 1;

    const int srow = tid >> 1;
    const int scol = (tid & 1) * 16;

    f32x4 acc[4][4];
#pragma unroll
    for (int mi = 0; mi < 4; mi++)
#pragma unroll
        for (int ni = 0; ni < 4; ni++) acc[mi][ni] = (f32x4){0.f, 0.f, 0.f, 0.f};

    for (int kb0 = 0; kb0 < 1024; kb0 += 32) {
        const unsigned short* ap = A + (size_t)(m0 + srow) * 1024 + kb0 + scol;
        uint4 a0 = *reinterpret_cast<const uint4*>(ap);
        uint4 a1 = *reinterpret_cast<const uint4*>(ap + 8);
        const unsigned short* wp = Wob + (size_t)(n0g + srow) * 1024 + kb0 + scol;
        uint4 b0 = *reinterpret_cast<const uint4*>(wp);
        uint4 b1 = *reinterpret_cast<const uint4*>(wp + 8);

        __syncthreads();
        {
            uint4* ad = reinterpret_cast<uint4*>(&As[srow][scol]);
            ad[0] = a0; ad[1] = a1;
            uint4* bd = reinterpret_cast<uint4*>(&Bs[srow][scol]);
            bd[0] = b0; bd[1] = b1;
        }
        __syncthreads();

        bf16x8 af[4], bfr[4];
#pragma unroll
        for (int mi = 0; mi < 4; mi++)
            af[mi] = *reinterpret_cast<const bf16x8*>(&As[qm * 64 + mi * 16 + c15][quad * 8]);
#pragma unroll
        for (int ni = 0; ni < 4; ni++)
            bfr[ni] = *reinterpret_cast<const bf16x8*>(&Bs[qn * 64 + ni * 16 + c15][quad * 8]);
#pragma unroll
        for (int mi = 0; mi < 4; mi++)
#pragma unroll
            for (int ni = 0; ni < 4; ni++)
                acc[mi][ni] = __builtin_amdgcn_mfma_f32_16x16x32_bf16(af[mi], bfr[ni], acc[mi][ni], 0, 0, 0);
    }

#pragma unroll
    for (int mi = 0; mi < 4; mi++) {
#pragma unroll
        for (int r = 0; r < 4; r++) {
            int m = m0 + qm * 64 + mi * 16 + quad * 4 + r;
#pragma unroll
            for (int ni = 0; ni < 4; ni++) {
                int n = n0g + qn * 64 + ni * 16 + c15;
                out[(size_t)m * 1024 + n] = acc[mi][ni][r];
            }
        }
    }
}

extern "C" void kernel_launch(void* const* d_in, const int* in_sizes, int n_in,
                              void* d_out, int out_size, void* d_ws, size_t ws_size,
                              hipStream_t stream)
{
    const float* x  = (const float*)d_in[0];
    const float* Wq = (const float*)d_in[1];
    const float* Wk = (const float*)d_in[2];
    const float* Wv = (const float*)d_in[3];
    const float* Wo = (const float*)d_in[4];
    float* out = (float*)d_out;

    const size_t QKV_ELEMS = (size_t)BATCH * SEQ * D_MODEL;  // 4194304

    unsigned short* qb = (unsigned short*)d_ws;
    unsigned short* kb = qb + QKV_ELEMS;
    unsigned short* vt = kb + QKV_ELEMS;   // [b][h][d][s]
    unsigned short* ab = vt + QKV_ELEMS;
    unsigned short* w3bf = ab;             // dead during qkv
    unsigned short* wobf = qb;             // dead during out

    conv_kernel<<<dim3(3072), 256, 0, stream>>>(Wq, w3bf, 262144);
    conv_kernel<<<dim3(3072), 256, 0, stream>>>(Wk, w3bf + 1048576, 262144);
    conv_kernel<<<dim3(3072), 256, 0, stream>>>(Wv, w3bf + 2097152, 262144);
    qkv_mfma_kernel<<<dim3(768), 256, 0, stream>>>(x, w3bf, qb, kb, vt);
    attn_kernel<<<dim3(32, 32), 256, 0, stream>>>(qb, kb, vt, ab);
    conv_kernel<<<dim3(1024), 256, 0, stream>>>(Wo, wobf, 262144);
    out_mfma_kernel<<<dim3(256), 256, 0, stream>>>(ab, wobf, out);
}

// Round 13
// 290.805 us; speedup vs baseline: 1.3831x; 1.3831x over previous
//
#include <hip/hip_runtime.h>

#define D_MODEL 1024
#define NUM_HEADS 16
#define SEQ 2048
#define BATCH 2

typedef __attribute__((ext_vector_type(8))) short bf16x8;
typedef __attribute__((ext_vector_type(4))) float f32x4;

__device__ __forceinline__ float bf2f(unsigned short u) {
    return __uint_as_float(((unsigned int)u) << 16);
}
__device__ __forceinline__ unsigned short f2bf(float f) {
    unsigned int u = __float_as_uint(f);
    return (unsigned short)((u + 0x7FFFu + ((u >> 16) & 1u)) >> 16);   // RTNE
}
__device__ __forceinline__ ushort4 pack4(float4 v) {
    return make_ushort4(f2bf(v.x), f2bf(v.y), f2bf(v.z), f2bf(v.w));
}

// fp32 -> bf16 bulk convert (one float4 -> ushort4 per thread).
__global__ __launch_bounds__(256) void conv_kernel(
    const float* __restrict__ src, unsigned short* __restrict__ dst, int n4)
{
    int i = blockIdx.x * 256 + threadIdx.x;
    if (i < n4) {
        float4 v = reinterpret_cast<const float4*>(src)[i];
        reinterpret_cast<ushort4*>(dst)[i] = pack4(v);
    }
}

// MFMA NT-GEMM: C[m,n] = sum_i x[m,i] * W[n,i]. x fp32, W bf16 (pre-converted).
// 128x128 tile, BK=32. 1D grid, XCD-swizzled: lin = b + 8*(which + 3*y).
// Q,K: RoPE fused, [b][h][s][d]. V: TRANSPOSED write [b][h][d][s].
__global__ __launch_bounds__(256) void qkv_mfma_kernel(
    const float* __restrict__ x,
    const unsigned short* __restrict__ w3,   // [3][1024][1024] bf16
    unsigned short* __restrict__ qb, unsigned short* __restrict__ kb,
    unsigned short* __restrict__ vt)
{
    const int lin = blockIdx.x;
    const int b = lin & 7;
    const int t = lin >> 3;
    const int which = t % 3;
    const int y = t / 3;
    const unsigned short* __restrict__ W = w3 + (size_t)which * 1048576;
    const int m0 = y * 128;
    const int n0g = b * 128;

    __shared__ __align__(16) unsigned short As[128][40];  // 80 B stride
    __shared__ __align__(16) unsigned short Bs[128][40];

    const int tid = threadIdx.x;
    const int w = tid >> 6;
    const int lane = tid & 63;
    const int quad = lane >> 4;
    const int c15 = lane & 15;
    const int qm = w >> 1, qn = w & 1;

    const int srow = tid >> 1;
    const int scol = (tid & 1) * 16;

    f32x4 acc[4][4];
#pragma unroll
    for (int mi = 0; mi < 4; mi++)
#pragma unroll
        for (int ni = 0; ni < 4; ni++) acc[mi][ni] = (f32x4){0.f, 0.f, 0.f, 0.f};

    for (int kb0 = 0; kb0 < 1024; kb0 += 32) {
        const float* ap = x + (size_t)(m0 + srow) * 1024 + kb0 + scol;
        float4 a0 = *reinterpret_cast<const float4*>(ap + 0);
        float4 a1 = *reinterpret_cast<const float4*>(ap + 4);
        float4 a2 = *reinterpret_cast<const float4*>(ap + 8);
        float4 a3 = *reinterpret_cast<const float4*>(ap + 12);
        const unsigned short* wp = W + (size_t)(n0g + srow) * 1024 + kb0 + scol;
        uint4 b0 = *reinterpret_cast<const uint4*>(wp);
        uint4 b1 = *reinterpret_cast<const uint4*>(wp + 8);

        __syncthreads();
        {
            ushort4* ad = reinterpret_cast<ushort4*>(&As[srow][scol]);
            ad[0] = pack4(a0); ad[1] = pack4(a1); ad[2] = pack4(a2); ad[3] = pack4(a3);
            uint4* bd = reinterpret_cast<uint4*>(&Bs[srow][scol]);
            bd[0] = b0; bd[1] = b1;
        }
        __syncthreads();

        bf16x8 af[4], bfr[4];
#pragma unroll
        for (int mi = 0; mi < 4; mi++)
            af[mi] = *reinterpret_cast<const bf16x8*>(&As[qm * 64 + mi * 16 + c15][quad * 8]);
#pragma unroll
        for (int ni = 0; ni < 4; ni++)
            bfr[ni] = *reinterpret_cast<const bf16x8*>(&Bs[qn * 64 + ni * 16 + c15][quad * 8]);
#pragma unroll
        for (int mi = 0; mi < 4; mi++)
#pragma unroll
            for (int ni = 0; ni < 4; ni++)
                acc[mi][ni] = __builtin_amdgcn_mfma_f32_16x16x32_bf16(af[mi], bfr[ni], acc[mi][ni], 0, 0, 0);
    }

    // Epilogue: RoPE (Q,K) in registers -> wave-private LDS stage -> coalesced
    // stores. Wave's n-range = one head: h = b*2 + qn.
    __syncthreads();
    unsigned short* stg = &As[0][0] + w * (16 * 72);   // 16 rows x 72 stride, per wave
    const int hq = b * 2 + qn;
    unsigned short* outp = (which == 0) ? qb : kb;

    float invf[4];
#pragma unroll
    for (int ni = 0; ni < 4; ni++)
        invf[ni] = powf(10000.0f, -((float)(((ni * 16 + c15) & 63) >> 1)) / 32.0f);
    const int odd = c15 & 1;

#pragma unroll
    for (int mi = 0; mi < 4; mi++) {
#pragma unroll
        for (int r = 0; r < 4; r++) {
            int m = m0 + qm * 64 + mi * 16 + quad * 4 + r;
            int s = m & (SEQ - 1);
#pragma unroll
            for (int ni = 0; ni < 4; ni++) {
                float val = acc[mi][ni][r];
                float res;
                if (which < 2) {
                    float part = __shfl_xor(val, 1);
                    float sn, cs;
                    sincosf((float)s * invf[ni], &sn, &cs);
                    res = odd ? (part * sn + val * cs) : (val * cs - part * sn);
                } else {
                    res = val;
                }
                stg[(quad * 4 + r) * 72 + ni * 16 + c15] = f2bf(res);
            }
        }
        if (which < 2) {
            // rows of [s][d]: 4 lanes per row, 32 B each -> 128 B contiguous
            int row = lane >> 2;
            int ch = lane & 3;
            int m = m0 + qm * 64 + mi * 16 + row;
            int s = m & (SEQ - 1);
            int bb = m >> 11;
            size_t ob = (((size_t)bb * NUM_HEADS + hq) * SEQ + s) * 64 + ch * 16;
            uint4 v0 = *reinterpret_cast<const uint4*>(&stg[row * 72 + ch * 16]);
            uint4 v1 = *reinterpret_cast<const uint4*>(&stg[row * 72 + ch * 16 + 8]);
            *reinterpret_cast<uint4*>(&outp[ob]) = v0;
            *reinterpret_cast<uint4*>(&outp[ob + 8]) = v1;
        } else {
            // transposed write to vt[b][h][d][s]: lane = d, 16 s values = 32 B
            int mbase = m0 + qm * 64 + mi * 16;
            int bb = mbase >> 11;
            int s_base = mbase & (SEQ - 1);
            unsigned short tmp[16];
#pragma unroll
            for (int sl = 0; sl < 16; sl++) tmp[sl] = stg[sl * 72 + lane];
            size_t ob = (((size_t)bb * NUM_HEADS + hq) * 64 + lane) * SEQ + s_base;
            *reinterpret_cast<uint4*>(&vt[ob])     = *reinterpret_cast<uint4*>(&tmp[0]);
            *reinterpret_cast<uint4*>(&vt[ob + 8]) = *reinterpret_cast<uint4*>(&tmp[8]);
        }
    }
}

// MFMA flash attention, barrier-free, latency-balanced.
// Block (x, bh) processes Q-tiles {31-x, x} sequentially: every block = 33
// tile-iterations (perfect balance). K double-buffered in registers; V loads
// issued at iteration top so global latency hides behind the softmax chain.
__global__ __launch_bounds__(256) void attn_kernel(
    const unsigned short* __restrict__ qb, const unsigned short* __restrict__ kb,
    const unsigned short* __restrict__ vt, unsigned short* __restrict__ ab)
{
    const int xpair = blockIdx.x;   // 0..15
    const int bh = blockIdx.y;
    const int b = bh >> 4, h = bh & 15;
    const size_t base = (size_t)bh * SEQ * 64;     // qb/kb [b][h][s][d]
    const size_t vbase = (size_t)bh * 64 * SEQ;    // vt [b][h][d][s]
    const int tid = threadIdx.x;
    const int w = tid >> 6;
    const int lane = tid & 63;
    const int quad = lane >> 4;
    const int c15 = lane & 15;

    __shared__ __align__(16) unsigned short Pl[64][72];   // wave-private rows

    for (int pass = 0; pass < 2; pass++) {
        const int it = pass ? xpair : (31 - xpair);   // heavy tile first
        const int i0 = it * 64;

        const int qrow = i0 + w * 16 + c15;
        bf16x8 qf0 = *reinterpret_cast<const bf16x8*>(&qb[base + (size_t)qrow * 64 + quad * 8]);
        bf16x8 qf1 = *reinterpret_cast<const bf16x8*>(&qb[base + (size_t)qrow * 64 + 32 + quad * 8]);

        float m_st[4], l_st[4];
        f32x4 Oc[4];
#pragma unroll
        for (int r = 0; r < 4; r++) { m_st[r] = -1e30f; l_st[r] = 0.f; }
#pragma unroll
        for (int t = 0; t < 4; t++) Oc[t] = (f32x4){0.f, 0.f, 0.f, 0.f};

        // preload K fragments for jt = 0
        bf16x8 kc0[4], kc1[4];
#pragma unroll
        for (int t = 0; t < 4; t++) {
            const unsigned short* kr = &kb[base + (size_t)(t * 16 + c15) * 64];
            kc0[t] = *reinterpret_cast<const bf16x8*>(kr + quad * 8);
            kc1[t] = *reinterpret_cast<const bf16x8*>(kr + 32 + quad * 8);
        }

        for (int jt = 0; jt <= it; jt++) {
            const int j0 = jt * 64;

            // V loads for current jt — issued now, consumed after softmax
            bf16x8 vv0[4], vv1[4];
#pragma unroll
            for (int t = 0; t < 4; t++) {
                const unsigned short* vr = &vt[vbase + (size_t)(t * 16 + c15) * SEQ + j0];
                vv0[t] = *reinterpret_cast<const bf16x8*>(vr + quad * 8);
                vv1[t] = *reinterpret_cast<const bf16x8*>(vr + 32 + quad * 8);
            }
            // K prefetch for jt+1
            bf16x8 kn0[4], kn1[4];
            if (jt < it) {
#pragma unroll
                for (int t = 0; t < 4; t++) {
                    const unsigned short* kr = &kb[base + (size_t)(j0 + 64 + t * 16 + c15) * 64];
                    kn0[t] = *reinterpret_cast<const bf16x8*>(kr + quad * 8);
                    kn1[t] = *reinterpret_cast<const bf16x8*>(kr + 32 + quad * 8);
                }
            }

            f32x4 sc[4];
#pragma unroll
            for (int t = 0; t < 4; t++) sc[t] = (f32x4){0.f, 0.f, 0.f, 0.f};
#pragma unroll
            for (int t = 0; t < 4; t++) {
                sc[t] = __builtin_amdgcn_mfma_f32_16x16x32_bf16(qf0, kc0[t], sc[t], 0, 0, 0);
                sc[t] = __builtin_amdgcn_mfma_f32_16x16x32_bf16(qf1, kc1[t], sc[t], 0, 0, 0);
            }

#pragma unroll
            for (int t = 0; t < 4; t++)
#pragma unroll
                for (int r = 0; r < 4; r++) sc[t][r] *= 0.125f;
            if (jt == it) {
#pragma unroll
                for (int t = 0; t < 4; t++) {
                    int gj = j0 + t * 16 + c15;
#pragma unroll
                    for (int r = 0; r < 4; r++) {
                        int gi = i0 + w * 16 + quad * 4 + r;
                        if (gj > gi) sc[t][r] = -1e30f;
                    }
                }
            }

            float mnew[4], alpha[4], rsum[4];
#pragma unroll
            for (int r = 0; r < 4; r++) {
                float tm = fmaxf(fmaxf(sc[0][r], sc[1][r]), fmaxf(sc[2][r], sc[3][r]));
                tm = fmaxf(tm, __shfl_xor(tm, 1));
                tm = fmaxf(tm, __shfl_xor(tm, 2));
                tm = fmaxf(tm, __shfl_xor(tm, 4));
                tm = fmaxf(tm, __shfl_xor(tm, 8));
                mnew[r] = fmaxf(m_st[r], tm);
                alpha[r] = __expf(m_st[r] - mnew[r]);
                rsum[r] = 0.f;
            }
#pragma unroll
            for (int t = 0; t < 4; t++) {
#pragma unroll
                for (int r = 0; r < 4; r++) {
                    float p = __expf(sc[t][r] - mnew[r]);
                    rsum[r] += p;
                    Pl[w * 16 + quad * 4 + r][t * 16 + c15] = f2bf(p);
                }
            }
#pragma unroll
            for (int r = 0; r < 4; r++) {
                float s = rsum[r];
                s += __shfl_xor(s, 1);
                s += __shfl_xor(s, 2);
                s += __shfl_xor(s, 4);
                s += __shfl_xor(s, 8);
                l_st[r] = l_st[r] * alpha[r] + s;
                m_st[r] = mnew[r];
#pragma unroll
                for (int t = 0; t < 4; t++) Oc[t][r] *= alpha[r];
            }

            bf16x8 ap0 = *reinterpret_cast<const bf16x8*>(&Pl[w * 16 + c15][quad * 8]);
            bf16x8 ap1 = *reinterpret_cast<const bf16x8*>(&Pl[w * 16 + c15][32 + quad * 8]);
#pragma unroll
            for (int t = 0; t < 4; t++) {
                Oc[t] = __builtin_amdgcn_mfma_f32_16x16x32_bf16(ap0, vv0[t], Oc[t], 0, 0, 0);
                Oc[t] = __builtin_amdgcn_mfma_f32_16x16x32_bf16(ap1, vv1[t], Oc[t], 0, 0, 0);
            }

            if (jt < it) {
#pragma unroll
                for (int t = 0; t < 4; t++) { kc0[t] = kn0[t]; kc1[t] = kn1[t]; }
            }
        }

        // Epilogue: stage O into Pl, coalesced uint4 stores.
#pragma unroll
        for (int r = 0; r < 4; r++) {
            float inv = 1.0f / l_st[r];
#pragma unroll
            for (int t = 0; t < 4; t++)
                Pl[w * 16 + quad * 4 + r][t * 16 + c15] = f2bf(Oc[t][r] * inv);
        }
        {
            int row = lane >> 2;
            int ch = lane & 3;
            int gi = i0 + w * 16 + row;
            size_t ob = ((size_t)b * SEQ + gi) * 1024 + h * 64 + ch * 16;
            uint4 v0 = *reinterpret_cast<const uint4*>(&Pl[w * 16 + row][ch * 16]);
            uint4 v1 = *reinterpret_cast<const uint4*>(&Pl[w * 16 + row][ch * 16 + 8]);
            *reinterpret_cast<uint4*>(&ab[ob]) = v0;
            *reinterpret_cast<uint4*>(&ab[ob + 8]) = v1;
        }
    }
}

// MFMA NT-GEMM: out[m,n] = sum_i ab[m,i] * Wo[n,i]; both bf16, out fp32.
__global__ __launch_bounds__(256) void out_mfma_kernel(
    const unsigned short* __restrict__ A, const unsigned short* __restrict__ Wob,
    float* __restrict__ out)
{
    const int lin = blockIdx.x;
    const int b = lin & 7;
    const int y = lin >> 3;
    const int m0 = y * 128;
    const int n0g = b * 128;

    __shared__ __align__(16) unsigned short As[128][40];
    __shared__ __align__(16) unsigned short Bs[128][40];

    const int tid = threadIdx.x;
    const int w = tid >> 6;
    const int lane = tid & 63;
    const int quad = lane >> 4;
    const int c15 = lane & 15;
    const int qm = w >> 1, qn = w & 1;

    const int srow = tid >> 1;
    const int scol = (tid & 1) * 16;

    f32x4 acc[4][4];
#pragma unroll
    for (int mi = 0; mi < 4; mi++)
#pragma unroll
        for (int ni = 0; ni < 4; ni++) acc[mi][ni] = (f32x4){0.f, 0.f, 0.f, 0.f};

    for (int kb0 = 0; kb0 < 1024; kb0 += 32) {
        const unsigned short* ap = A + (size_t)(m0 + srow) * 1024 + kb0 + scol;
        uint4 a0 = *reinterpret_cast<const uint4*>(ap);
        uint4 a1 = *reinterpret_cast<const uint4*>(ap + 8);
        const unsigned short* wp = Wob + (size_t)(n0g + srow) * 1024 + kb0 + scol;
        uint4 b0 = *reinterpret_cast<const uint4*>(wp);
        uint4 b1 = *reinterpret_cast<const uint4*>(wp + 8);

        __syncthreads();
        {
            uint4* ad = reinterpret_cast<uint4*>(&As[srow][scol]);
            ad[0] = a0; ad[1] = a1;
            uint4* bd = reinterpret_cast<uint4*>(&Bs[srow][scol]);
            bd[0] = b0; bd[1] = b1;
        }
        __syncthreads();

        bf16x8 af[4], bfr[4];
#pragma unroll
        for (int mi = 0; mi < 4; mi++)
            af[mi] = *reinterpret_cast<const bf16x8*>(&As[qm * 64 + mi * 16 + c15][quad * 8]);
#pragma unroll
        for (int ni = 0; ni < 4; ni++)
            bfr[ni] = *reinterpret_cast<const bf16x8*>(&Bs[qn * 64 + ni * 16 + c15][quad * 8]);
#pragma unroll
        for (int mi = 0; mi < 4; mi++)
#pragma unroll
            for (int ni = 0; ni < 4; ni++)
                acc[mi][ni] = __builtin_amdgcn_mfma_f32_16x16x32_bf16(af[mi], bfr[ni], acc[mi][ni], 0, 0, 0);
    }

#pragma unroll
    for (int mi = 0; mi < 4; mi++) {
#pragma unroll
        for (int r = 0; r < 4; r++) {
            int m = m0 + qm * 64 + mi * 16 + quad * 4 + r;
#pragma unroll
            for (int ni = 0; ni < 4; ni++) {
                int n = n0g + qn * 64 + ni * 16 + c15;
                out[(size_t)m * 1024 + n] = acc[mi][ni][r];
            }
        }
    }
}

extern "C" void kernel_launch(void* const* d_in, const int* in_sizes, int n_in,
                              void* d_out, int out_size, void* d_ws, size_t ws_size,
                              hipStream_t stream)
{
    const float* x  = (const float*)d_in[0];
    const float* Wq = (const float*)d_in[1];
    const float* Wk = (const float*)d_in[2];
    const float* Wv = (const float*)d_in[3];
    const float* Wo = (const float*)d_in[4];
    float* out = (float*)d_out;

    const size_t QKV_ELEMS = (size_t)BATCH * SEQ * D_MODEL;  // 4194304

    unsigned short* qb = (unsigned short*)d_ws;
    unsigned short* kb = qb + QKV_ELEMS;
    unsigned short* vt = kb + QKV_ELEMS;   // [b][h][d][s]
    unsigned short* ab = vt + QKV_ELEMS;
    unsigned short* w3bf = ab;             // dead during qkv
    unsigned short* wobf = qb;             // dead during out

    conv_kernel<<<dim3(3072), 256, 0, stream>>>(Wq, w3bf, 262144);
    conv_kernel<<<dim3(3072), 256, 0, stream>>>(Wk, w3bf + 1048576, 262144);
    conv_kernel<<<dim3(3072), 256, 0, stream>>>(Wv, w3bf + 2097152, 262144);
    qkv_mfma_kernel<<<dim3(768), 256, 0, stream>>>(x, w3bf, qb, kb, vt);
    attn_kernel<<<dim3(16, 32), 256, 0, stream>>>(qb, kb, vt, ab);
    conv_kernel<<<dim3(1024), 256, 0, stream>>>(Wo, wobf, 262144);
    out_mfma_kernel<<<dim3(256), 256, 0, stream>>>(ab, wobf, out);
}